// Round 11
// baseline (251.505 us; speedup 1.0000x reference)
//
#include <hip/hip_runtime.h>
#include <hip/hip_bf16.h>
#include <math.h>

#define SEQ 4096
#define DM  768
#define NH  12
#define HD  64
#define PER ((size_t)NH * SEQ * HD)       // 3,145,728
#define XN  ((size_t)SEQ * DM)
#define WN  ((size_t)DM * DM)

typedef __attribute__((ext_vector_type(8))) short bf16x8;   // MFMA A/B frag
typedef __attribute__((ext_vector_type(4))) short s16x4;
typedef __attribute__((ext_vector_type(4))) float f32x4;    // MFMA C/D frag

#define MFMA(a, b, c) __builtin_amdgcn_mfma_f32_16x16x32_bf16((a), (b), (c), 0, 0, 0)

#if __has_builtin(__builtin_amdgcn_exp2f)
#define EXP2(x) __builtin_amdgcn_exp2f(x)
#else
#define EXP2(x) exp2f(x)
#endif

// XOR-swizzled 64-wide bf16 LDS tile, 16B blocks (conflict-free b128).
#define SWZ(row, blk) (((row) << 6) + ((((blk) ^ ((row) & 7))) << 3))

// fast RTNE fp32->bf16 (finite values only)
__device__ __forceinline__ unsigned short f2b(float f) {
    unsigned int u = __float_as_uint(f);
    u += 0x7FFFu + ((u >> 16) & 1u);
    return (unsigned short)(u >> 16);
}

// ---------------------------------------------------------------------------
// Prep: ONE kernel converts x + 4 weights fp32->bf16 and fills the RoPE table.
// ---------------------------------------------------------------------------
__global__ __launch_bounds__(256) void prep_kernel(
    const float* __restrict__ x,  const float* __restrict__ wq,
    const float* __restrict__ wk, const float* __restrict__ wv,
    const float* __restrict__ wo,
    unsigned short* __restrict__ dstbase, float2* __restrict__ rope)
{
    const float* srcs[5] = {x, wq, wk, wv, wo};
    const size_t n4s[5]  = {XN / 4, WN / 4, WN / 4, WN / 4, WN / 4};
    unsigned short* d = dstbase;
    for (int rg = 0; rg < 5; ++rg) {
        const float4* s4 = (const float4*)srcs[rg];
        s16x4* d4 = (s16x4*)d;
        for (size_t i = (size_t)blockIdx.x * 256 + threadIdx.x; i < n4s[rg];
             i += (size_t)gridDim.x * 256) {
            const float4 v = s4[i];
            s16x4 p;
            p.x = (short)f2b(v.x); p.y = (short)f2b(v.y);
            p.z = (short)f2b(v.z); p.w = (short)f2b(v.w);
            d4[i] = p;
        }
        d += n4s[rg] * 4;
    }
    for (int g = blockIdx.x * 256 + threadIdx.x; g < 131072; g += gridDim.x * 256) {
        const int row = g >> 5, fi = g & 31;
        const float invf = expf(-(float)fi * 0.28782313662425576f);
        float sn, cs;
        sincosf((float)row * invf, &sn, &cs);
        rope[row * 32 + fi] = make_float2(cs, sn);
    }
}

// ---------------------------------------------------------------------------
// K1: QKV projection (x @ W.T, MFMA) — unchanged from round 10.
// ---------------------------------------------------------------------------
__global__ __launch_bounds__(256) void qkv_mfma(
    const float* __restrict__ x,  const unsigned short* __restrict__ xb,
    const float* __restrict__ Wq, const float* __restrict__ Wk, const float* __restrict__ Wv,
    const unsigned short* __restrict__ Wqb, const unsigned short* __restrict__ Wkb,
    const unsigned short* __restrict__ Wvb,
    const float2* __restrict__ rope,
    unsigned short* __restrict__ Qo, unsigned short* __restrict__ Ko,
    unsigned short* __restrict__ Vo, int fast)
{
    __shared__ __align__(16) unsigned short Xs[2][4096];
    __shared__ __align__(16) unsigned short Ws[2][4096];
    __shared__ unsigned short VL[64 * 66];

    const int t    = threadIdx.x;
    const int w    = t >> 6;
    const int lane = t & 63;
    const int quad = lane >> 4;
    const int l16  = lane & 15;

    const int nt_b = blockIdx.y;
    const float* W; const unsigned short* Wb; int region;
    if (nt_b < 12)      { W = Wq; Wb = Wqb; region = 0; }
    else if (nt_b < 24) { W = Wk; Wb = Wkb; region = 1; }
    else                { W = Wv; Wb = Wvb; region = 2; }
    const int h  = nt_b % 12;
    const int s0 = blockIdx.x * 64;
    const int n0 = h * 64;

    f32x4 acc[4] = {{0,0,0,0},{0,0,0,0},{0,0,0,0},{0,0,0,0}};
    const int prow = t >> 3, pblk = t & 7;

    bf16x8 xr0, xr1, wr0, wr1;
    if (fast) {
        xr0 = *(const bf16x8*)&xb[(size_t)(s0 + prow) * DM + pblk * 8];
        xr1 = *(const bf16x8*)&xb[(size_t)(s0 + prow + 32) * DM + pblk * 8];
        wr0 = *(const bf16x8*)&Wb[(size_t)(n0 + prow) * DM + pblk * 8];
        wr1 = *(const bf16x8*)&Wb[(size_t)(n0 + prow + 32) * DM + pblk * 8];
        *(bf16x8*)&Xs[0][SWZ(prow, pblk)]      = xr0;
        *(bf16x8*)&Xs[0][SWZ(prow + 32, pblk)] = xr1;
        *(bf16x8*)&Ws[0][SWZ(prow, pblk)]      = wr0;
        *(bf16x8*)&Ws[0][SWZ(prow + 32, pblk)] = wr1;
    } else {
        for (int e = t; e < 1024; e += 256) {
            const int row = e >> 4, c4 = e & 15;
            const int off = SWZ(row, c4 >> 1) + (c4 & 1) * 4;
            const float4 xv = *(const float4*)&x[(size_t)(s0 + row) * DM + c4 * 4];
            s16x4 px; px.x = (short)f2b(xv.x); px.y = (short)f2b(xv.y);
            px.z = (short)f2b(xv.z); px.w = (short)f2b(xv.w);
            *(s16x4*)&Xs[0][off] = px;
            const float4 wv = *(const float4*)&W[(size_t)(n0 + row) * DM + c4 * 4];
            s16x4 pw; pw.x = (short)f2b(wv.x); pw.y = (short)f2b(wv.y);
            pw.z = (short)f2b(wv.z); pw.w = (short)f2b(wv.w);
            *(s16x4*)&Ws[0][off] = pw;
        }
    }
    __syncthreads();

    for (int kt = 0; kt < 12; ++kt) {
        const unsigned short* Xb  = Xs[kt & 1];
        const unsigned short* Wbt = Ws[kt & 1];
        if (fast && kt < 11) {
            const int k0 = (kt + 1) * 64;
            xr0 = *(const bf16x8*)&xb[(size_t)(s0 + prow) * DM + k0 + pblk * 8];
            xr1 = *(const bf16x8*)&xb[(size_t)(s0 + prow + 32) * DM + k0 + pblk * 8];
            wr0 = *(const bf16x8*)&Wb[(size_t)(n0 + prow) * DM + k0 + pblk * 8];
            wr1 = *(const bf16x8*)&Wb[(size_t)(n0 + prow + 32) * DM + k0 + pblk * 8];
        }
        const bf16x8 a0 = *(const bf16x8*)&Xb[SWZ(16 * w + l16, quad)];
        const bf16x8 a1 = *(const bf16x8*)&Xb[SWZ(16 * w + l16, 4 + quad)];
        #pragma unroll
        for (int nt = 0; nt < 4; ++nt) {
            const bf16x8 b0 = *(const bf16x8*)&Wbt[SWZ(16 * nt + l16, quad)];
            const bf16x8 b1 = *(const bf16x8*)&Wbt[SWZ(16 * nt + l16, 4 + quad)];
            acc[nt] = MFMA(a0, b0, acc[nt]);
            acc[nt] = MFMA(a1, b1, acc[nt]);
        }
        if (kt < 11) {
            const int nb = (kt + 1) & 1;
            if (fast) {
                *(bf16x8*)&Xs[nb][SWZ(prow, pblk)]      = xr0;
                *(bf16x8*)&Xs[nb][SWZ(prow + 32, pblk)] = xr1;
                *(bf16x8*)&Ws[nb][SWZ(prow, pblk)]      = wr0;
                *(bf16x8*)&Ws[nb][SWZ(prow + 32, pblk)] = wr1;
            } else {
                const int k0 = (kt + 1) * 64;
                for (int e = t; e < 1024; e += 256) {
                    const int row = e >> 4, c4 = e & 15;
                    const int off = SWZ(row, c4 >> 1) + (c4 & 1) * 4;
                    const float4 xv = *(const float4*)&x[(size_t)(s0 + row) * DM + k0 + c4 * 4];
                    s16x4 px; px.x = (short)f2b(xv.x); px.y = (short)f2b(xv.y);
                    px.z = (short)f2b(xv.z); px.w = (short)f2b(xv.w);
                    *(s16x4*)&Xs[nb][off] = px;
                    const float4 wv = *(const float4*)&W[(size_t)(n0 + row) * DM + k0 + c4 * 4];
                    s16x4 pw; pw.x = (short)f2b(wv.x); pw.y = (short)f2b(wv.y);
                    pw.z = (short)f2b(wv.z); pw.w = (short)f2b(wv.w);
                    *(s16x4*)&Ws[nb][off] = pw;
                }
            }
        }
        __syncthreads();
    }

    const size_t headoff = (size_t)h * SEQ * HD;
    if (region <= 1) {
        unsigned short* dst = (region == 0) ? Qo : Ko;
        const float qsc = (region == 0) ? 0.18033688011112042f : 1.0f;   // 0.125*log2e
        #pragma unroll
        for (int nt = 0; nt < 4; ++nt)
            #pragma unroll
            for (int r = 0; r < 4; ++r) {
                const int srow = s0 + 16 * w + quad * 4 + r;
                const int d  = nt * 16 + l16;
                const int fi = d >> 1;
                const float own = acc[nt][r] * qsc;
                const float oth = __shfl_xor(own, 1);
                float cs, sn;
                if (fast) {
                    const float2 t2 = rope[srow * 32 + fi];
                    cs = t2.x; sn = t2.y;
                } else {
                    const float invf = expf(-(float)fi * 0.28782313662425576f);
                    sincosf((float)srow * invf, &sn, &cs);
                }
                const float val = (d & 1) ? (oth * sn + own * cs)
                                          : (own * cs - oth * sn);
                dst[headoff + (size_t)srow * HD + ((d & 1) ? 32 : 0) + fi] = f2b(val);
            }
    } else {
        #pragma unroll
        for (int nt = 0; nt < 4; ++nt)
            #pragma unroll
            for (int r = 0; r < 4; ++r)
                VL[(nt * 16 + l16) * 66 + 16 * w + quad * 4 + r] = f2b(acc[nt][r]);
        __syncthreads();
        for (int e = t; e < 2048; e += 256) {
            const int d = e >> 5, sp = e & 31;
            const unsigned int v = (unsigned int)VL[d * 66 + 2 * sp] |
                                   ((unsigned int)VL[d * 66 + 2 * sp + 1] << 16);
            *(unsigned int*)&Vo[headoff + (size_t)d * SEQ + s0 + 2 * sp] = v;
        }
    }
}

// ---------------------------------------------------------------------------
// K2: causal flash attention, BARRIER-FREE chunk loop. Q/K/V MFMA fragments
// are loaded DIRECTLY global->VGPR per lane (the per-lane addresses are
// exactly what the old LDS swizzle reconstructed):
//   A-frag  [m=l16][k=8*quad+j]  -> &Q[(q0+16qt+l16)*64 + 32*hh + 8*quad]
//   K B-frag                      -> &K[(key_row)*64 + 32*hh + 8*quad]
//   V^T A-frag                    -> &V[(16dt+l16)*SEQ + k0+32w + 8*quad]
// Only the wave-private P strip (C->A layout) stays in LDS (lgkmcnt only).
// bK register-double-buffered across chunks; aV issued at body top.
// Same block mapping as round 10 (split grid (96,12), fp32 partials).
// ---------------------------------------------------------------------------
__global__ __launch_bounds__(256, 2) void attn_mfma(
    const unsigned short* __restrict__ Q,    // [h][seq][64], pre-scaled
    const unsigned short* __restrict__ K,    // [h][seq][64]
    const unsigned short* __restrict__ V,    // [h][64][seq]  (transposed)
    unsigned short* __restrict__ O,          // [4096][768]
    float* __restrict__ Part)                // [384][2][4160] fp32 partials
{
    __shared__ __align__(16) unsigned char SM[38912];
    unsigned short* Ps = (unsigned short*)SM;            // 4 strips 64x40 = 20,480B
    float* ACC  = (float*)SM;                            // epilogue 64x72 = 18,432B
    float* ACC2 = (float*)(SM + 18432);                  // 18,432B
    float* Lx   = (float*)(SM + 36864);                  // 4x64 fp32 = 1,024B

    const int h  = blockIdx.y;
    const int xx = blockIdx.x;
    int i, kstart, nch, domask, partial, pslice;
    if (gridDim.x == 96) {
        if (xx < 64) {
            i = 63 - xx; kstart = 0;
            const int full = ((i * 64 + 63) >> 7) + 1;
            nch = full < 16 ? full : 16;
            domask  = (i <= 31);
            partial = (i >= 32); pslice = 0;
        } else {
            i = 127 - xx; kstart = 2048;
            nch = ((i * 64 + 63 - 2048) >> 7) + 1;
            domask = 1; partial = 1; pslice = 1;
        }
    } else {
        i = 63 - xx; kstart = 0;
        nch = ((i * 64 + 63) >> 7) + 1;
        domask = 1; partial = 0; pslice = 0;
    }
    const int q0 = i * 64;

    const int t    = threadIdx.x;
    const int w    = t >> 6;
    const int lane = t & 63;
    const int quad = lane >> 4;
    const int l16  = lane & 15;
    const size_t headoff = (size_t)h * SEQ * HD;
    const unsigned short* Qh = Q + headoff;
    const unsigned short* Kh = K + headoff;
    const unsigned short* Vh = V + headoff;

    // ---- Q A-frags: direct global loads, no LDS, no barrier ----
    bf16x8 aQ[4][2];
    #pragma unroll
    for (int qt = 0; qt < 4; ++qt)
        #pragma unroll
        for (int hh = 0; hh < 2; ++hh)
            aQ[qt][hh] = *(const bf16x8*)&Qh[(size_t)(q0 + 16 * qt + l16) * HD +
                                             32 * hh + 8 * quad];

    // ---- bK for chunk 0 (register prefetch buffer) ----
    bf16x8 bK[2][2];
    #pragma unroll
    for (int kt = 0; kt < 2; ++kt)
        #pragma unroll
        for (int hh = 0; hh < 2; ++hh)
            bK[kt][hh] = *(const bf16x8*)&Kh[(size_t)(kstart + 32 * w + 16 * kt + l16) * HD +
                                             32 * hh + 8 * quad];

    bf16x8 ones;
    #pragma unroll
    for (int ii = 0; ii < 8; ++ii) ones[ii] = (short)0x3F80;

    f32x4 oT[4][4];
    #pragma unroll
    for (int dt = 0; dt < 4; ++dt)
        #pragma unroll
        for (int qt = 0; qt < 4; ++qt) oT[dt][qt] = (f32x4){0,0,0,0};
    f32x4 lT[4] = {{0,0,0,0},{0,0,0,0},{0,0,0,0},{0,0,0,0}};

    unsigned short* usp = Ps + w * 2560;     // wave-private strip, stride 40

    for (int c = 0; c < nch; ++c) {
        const int k0 = kstart + c * 128;
        const int kw = k0 + 32 * w;          // wave's first key this chunk

        // V^T A-frags for THIS chunk (consumed after softmax, ~400 cyc cover)
        bf16x8 aV[4];
        #pragma unroll
        for (int dt = 0; dt < 4; ++dt)
            aV[dt] = *(const bf16x8*)&Vh[(size_t)(16 * dt + l16) * SEQ + kw + 8 * quad];

        // bK for NEXT chunk (consumed at next iteration's QK)
        bf16x8 bKn[2][2];
        if (c + 1 < nch) {
            const int kn = k0 + 128 + 32 * w;
            #pragma unroll
            for (int kt = 0; kt < 2; ++kt)
                #pragma unroll
                for (int hh = 0; hh < 2; ++hh)
                    bKn[kt][hh] = *(const bf16x8*)&Kh[(size_t)(kn + 16 * kt + l16) * HD +
                                                      32 * hh + 8 * quad];
        }

        // S = Q K^T for the wave's 32 keys
        f32x4 sC[4][2];
        #pragma unroll
        for (int qt = 0; qt < 4; ++qt)
            #pragma unroll
            for (int kt = 0; kt < 2; ++kt) sC[qt][kt] = (f32x4){0,0,0,0};
        #pragma unroll
        for (int kt = 0; kt < 2; ++kt)
            #pragma unroll
            for (int hh = 0; hh < 2; ++hh)
                #pragma unroll
                for (int qt = 0; qt < 4; ++qt)
                    sC[qt][kt] = MFMA(aQ[qt][hh], bK[kt][hh], sC[qt][kt]);

        if (domask && c == nch - 1) {        // causal mask, last chunk only
            #pragma unroll
            for (int kt = 0; kt < 2; ++kt) {
                const int key = k0 + 32 * w + 16 * kt + l16;
                #pragma unroll
                for (int qt = 0; qt < 4; ++qt)
                    #pragma unroll
                    for (int r = 0; r < 4; ++r)
                        if (key > q0 + 16 * qt + 4 * quad + r) sC[qt][kt][r] = -1e30f;
            }
        }

        // P = exp2(S) -> wave-private strip (C-layout -> [q][key] rows)
        #pragma unroll
        for (int qt = 0; qt < 4; ++qt)
            #pragma unroll
            for (int kt = 0; kt < 2; ++kt)
                #pragma unroll
                for (int r = 0; r < 4; ++r)
                    usp[(16 * qt + 4 * quad + r) * 40 + 16 * kt + l16] =
                        f2b(EXP2(sC[qt][kt][r]));
        asm volatile("s_waitcnt lgkmcnt(0)" ::: "memory");   // wave-local

        // O^T += V^T P^T ; l += ones @ P
        #pragma unroll
        for (int qt = 0; qt < 4; ++qt) {
            const bf16x8 bP = *(const bf16x8*)&usp[(16 * qt + l16) * 40 + quad * 8];
            lT[qt] = MFMA(ones, bP, lT[qt]);
            #pragma unroll
            for (int dt = 0; dt < 4; ++dt)
                oT[dt][qt] = MFMA(aV[dt], bP, oT[dt][qt]);
        }

        if (c + 1 < nch) {
            #pragma unroll
            for (int kt = 0; kt < 2; ++kt)
                #pragma unroll
                for (int hh = 0; hh < 2; ++hh)
                    bK[kt][hh] = bKn[kt][hh];
        }
    }

    __syncthreads();   // strips dead; ACC/Lx (aliasing them) now safe to write

    // ---- cross-wave reduction of O^T and l ----
    if (w != 0 && quad == 0) {
        #pragma unroll
        for (int qt = 0; qt < 4; ++qt)
            Lx[w * 64 + 16 * qt + l16] = lT[qt][0];
    }
    if (w == 1) {
        #pragma unroll
        for (int dt = 0; dt < 4; ++dt)
            #pragma unroll
            for (int qt = 0; qt < 4; ++qt)
                *(f32x4*)&ACC[(16 * qt + l16) * 72 + 16 * dt + 4 * quad] = oT[dt][qt];
    }
    __syncthreads();
    if (w == 0) {
        #pragma unroll
        for (int dt = 0; dt < 4; ++dt)
            #pragma unroll
            for (int qt = 0; qt < 4; ++qt)
                oT[dt][qt] += *(const f32x4*)&ACC[(16 * qt + l16) * 72 + 16 * dt + 4 * quad];
    }
    if (w == 2) {
        #pragma unroll
        for (int dt = 0; dt < 4; ++dt)
            #pragma unroll
            for (int qt = 0; qt < 4; ++qt)
                *(f32x4*)&ACC2[(16 * qt + l16) * 72 + 16 * dt + 4 * quad] = oT[dt][qt];
    }
    __syncthreads();
    if (w == 0) {
        #pragma unroll
        for (int dt = 0; dt < 4; ++dt)
            #pragma unroll
            for (int qt = 0; qt < 4; ++qt)
                oT[dt][qt] += *(const f32x4*)&ACC2[(16 * qt + l16) * 72 + 16 * dt + 4 * quad];
    }
    if (w == 3) {
        #pragma unroll
        for (int dt = 0; dt < 4; ++dt)
            #pragma unroll
            for (int qt = 0; qt < 4; ++qt)
                *(f32x4*)&ACC[(16 * qt + l16) * 72 + 16 * dt + 4 * quad] = oT[dt][qt];
    }
    __syncthreads();
    if (w == 0) {
        float ls[4];
        #pragma unroll
        for (int qt = 0; qt < 4; ++qt) {
            #pragma unroll
            for (int dt = 0; dt < 4; ++dt)
                oT[dt][qt] += *(const f32x4*)&ACC[(16 * qt + l16) * 72 + 16 * dt + 4 * quad];
            ls[qt] = lT[qt][0] + Lx[64 + 16 * qt + l16] +
                     Lx[128 + 16 * qt + l16] + Lx[192 + 16 * qt + l16];
        }
        if (!partial) {
            #pragma unroll
            for (int qt = 0; qt < 4; ++qt) {
                const float inv = 1.0f / ls[qt];
                const size_t rowoff = (size_t)(q0 + 16 * qt + l16) * DM + h * HD;
                #pragma unroll
                for (int dt = 0; dt < 4; ++dt) {
                    ushort4 u;
                    u.x = f2b(oT[dt][qt][0] * inv);
                    u.y = f2b(oT[dt][qt][1] * inv);
                    u.z = f2b(oT[dt][qt][2] * inv);
                    u.w = f2b(oT[dt][qt][3] * inv);
                    *(ushort4*)&O[rowoff + 16 * dt + 4 * quad] = u;
                }
            }
        } else {
            // [q][d] layout: oT[dt][qt][r] = O[q=16qt+l16][d=16dt+4quad+r]
            float* P = Part + (size_t)(((i - 32) * 12 + h) * 2 + pslice) * 4160;
            #pragma unroll
            for (int dt = 0; dt < 4; ++dt)
                #pragma unroll
                for (int qt = 0; qt < 4; ++qt)
                    *(f32x4*)&P[(16 * qt + l16) * 64 + 16 * dt + 4 * quad] = oT[dt][qt];
            if (quad == 0) {
                #pragma unroll
                for (int qt = 0; qt < 4; ++qt)
                    P[4096 + 16 * qt + l16] = ls[qt];
            }
        }
    }
}

// ---------------------------------------------------------------------------
// K2b: combine the two key-slices for q-tiles 32..63 — unchanged from r10.
// ---------------------------------------------------------------------------
__global__ __launch_bounds__(256) void reduce_attn(
    const float* __restrict__ Part, unsigned short* __restrict__ O)
{
    const int b  = blockIdx.x;
    const int i  = 32 + b / 12, h = b % 12;
    const int q0 = i * 64;
    const float* P0 = Part + (size_t)(b * 2 + 0) * 4160;
    const float* P1 = Part + (size_t)(b * 2 + 1) * 4160;
    __shared__ float linv[64];
    const int t = threadIdx.x;
    if (t < 64) linv[t] = 1.0f / (P0[4096 + t] + P1[4096 + t]);
    __syncthreads();
    for (int idx = t; idx < 4096; idx += 256) {
        const int q = idx >> 6, d = idx & 63;
        const float v = (P0[q * 64 + d] + P1[q * 64 + d]) * linv[q];
        O[(size_t)(q0 + q) * DM + h * HD + d] = f2b(v);
    }
}

// ---------------------------------------------------------------------------
// K3: output projection out = A @ Wo.T + bo (MFMA) — unchanged from round 10.
// ---------------------------------------------------------------------------
__global__ __launch_bounds__(256) void proj_mfma(
    const unsigned short* __restrict__ A,
    const float* __restrict__ Wo, const unsigned short* __restrict__ Wob,
    const float* __restrict__ bo,
    float* __restrict__ out, int fast)
{
    __shared__ __align__(16) unsigned short Xs[2][4096];
    __shared__ __align__(16) unsigned short Ws[2][4096];

    const int t    = threadIdx.x;
    const int w    = t >> 6;
    const int lane = t & 63;
    const int quad = lane >> 4;
    const int l16  = lane & 15;
    const int s0 = blockIdx.x * 64;
    const int n0 = blockIdx.y * 64;
    const int prow = t >> 3, pblk = t & 7;

    f32x4 acc[4] = {{0,0,0,0},{0,0,0,0},{0,0,0,0},{0,0,0,0}};

    bf16x8 ar0, ar1, wr0, wr1;
    ar0 = *(const bf16x8*)&A[(size_t)(s0 + prow) * DM + pblk * 8];
    ar1 = *(const bf16x8*)&A[(size_t)(s0 + prow + 32) * DM + pblk * 8];
    *(bf16x8*)&Xs[0][SWZ(prow, pblk)]      = ar0;
    *(bf16x8*)&Xs[0][SWZ(prow + 32, pblk)] = ar1;
    if (fast) {
        wr0 = *(const bf16x8*)&Wob[(size_t)(n0 + prow) * DM + pblk * 8];
        wr1 = *(const bf16x8*)&Wob[(size_t)(n0 + prow + 32) * DM + pblk * 8];
        *(bf16x8*)&Ws[0][SWZ(prow, pblk)]      = wr0;
        *(bf16x8*)&Ws[0][SWZ(prow + 32, pblk)] = wr1;
    } else {
        for (int e = t; e < 1024; e += 256) {
            const int row = e >> 4, c4 = e & 15;
            const float4 wv = *(const float4*)&Wo[(size_t)(n0 + row) * DM + c4 * 4];
            s16x4 pw; pw.x = (short)f2b(wv.x); pw.y = (short)f2b(wv.y);
            pw.z = (short)f2b(wv.z); pw.w = (short)f2b(wv.w);
            *(s16x4*)&Ws[0][SWZ(row, c4 >> 1) + (c4 & 1) * 4] = pw;
        }
    }
    __syncthreads();

    for (int kt = 0; kt < 12; ++kt) {
        const unsigned short* Xb  = Xs[kt & 1];
        const unsigned short* Wbt = Ws[kt & 1];
        if (kt < 11) {
            const int k0 = (kt + 1) * 64;
            ar0 = *(const bf16x8*)&A[(size_t)(s0 + prow) * DM + k0 + pblk * 8];
            ar1 = *(const bf16x8*)&A[(size_t)(s0 + prow + 32) * DM + k0 + pblk * 8];
            if (fast) {
                wr0 = *(const bf16x8*)&Wob[(size_t)(n0 + prow) * DM + k0 + pblk * 8];
                wr1 = *(const bf16x8*)&Wob[(size_t)(n0 + prow + 32) * DM + k0 + pblk * 8];
            }
        }
        const bf16x8 a0 = *(const bf16x8*)&Xb[SWZ(16 * w + l16, quad)];
        const bf16x8 a1 = *(const bf16x8*)&Xb[SWZ(16 * w + l16, 4 + quad)];
        #pragma unroll
        for (int nt = 0; nt < 4; ++nt) {
            const bf16x8 b0 = *(const bf16x8*)&Wbt[SWZ(16 * nt + l16, quad)];
            const bf16x8 b1 = *(const bf16x8*)&Wbt[SWZ(16 * nt + l16, 4 + quad)];
            acc[nt] = MFMA(a0, b0, acc[nt]);
            acc[nt] = MFMA(a1, b1, acc[nt]);
        }
        if (kt < 11) {
            const int nb = (kt + 1) & 1;
            *(bf16x8*)&Xs[nb][SWZ(prow, pblk)]      = ar0;
            *(bf16x8*)&Xs[nb][SWZ(prow + 32, pblk)] = ar1;
            if (fast) {
                *(bf16x8*)&Ws[nb][SWZ(prow, pblk)]      = wr0;
                *(bf16x8*)&Ws[nb][SWZ(prow + 32, pblk)] = wr1;
            } else {
                const int k0 = (kt + 1) * 64;
                for (int e = t; e < 1024; e += 256) {
                    const int row = e >> 4, c4 = e & 15;
                    const float4 wv = *(const float4*)&Wo[(size_t)(n0 + row) * DM + k0 + c4 * 4];
                    s16x4 pw; pw.x = (short)f2b(wv.x); pw.y = (short)f2b(wv.y);
                    pw.z = (short)f2b(wv.z); pw.w = (short)f2b(wv.w);
                    *(s16x4*)&Ws[nb][SWZ(row, c4 >> 1) + (c4 & 1) * 4] = pw;
                }
            }
        }
        __syncthreads();
    }

    #pragma unroll
    for (int nt = 0; nt < 4; ++nt)
        #pragma unroll
        for (int r = 0; r < 4; ++r) {
            const int srow = s0 + 16 * w + quad * 4 + r;
            const int n    = n0 + nt * 16 + l16;
            out[(size_t)srow * DM + n] = acc[nt][r] + bo[n];
        }
}

// ---------------------------------------------------------------------------
extern "C" void kernel_launch(void* const* d_in, const int* in_sizes, int n_in,
                              void* d_out, int out_size, void* d_ws, size_t ws_size,
                              hipStream_t stream) {
    const float* x  = (const float*)d_in[0];
    const float* Wq = (const float*)d_in[2];
    const float* Wk = (const float*)d_in[3];
    const float* Wv = (const float*)d_in[4];
    const float* Wo = (const float*)d_in[5];
    const float* bo = (const float*)d_in[6];
    float* out = (float*)d_out;

    unsigned short* U  = (unsigned short*)d_ws;
    unsigned short* Qw = U;
    unsigned short* Kw = U + PER;
    unsigned short* Vw = U + 2 * PER;    // transposed [h][64][seq]
    unsigned short* Ow = U + 3 * PER;    // [4096][768]
    unsigned short* xb  = U + 4 * PER;
    unsigned short* Wqb = xb + XN;
    unsigned short* Wkb = Wqb + WN;
    unsigned short* Wvb = Wkb + WN;
    unsigned short* Wob = Wvb + WN;
    float2* rope = (float2*)(Wob + WN);  // [4096][32]
    float*  part = (float*)(rope + 4096 * 32);   // [384][2][4160] fp32
    const size_t need  = (char*)part - (char*)d_ws;
    const size_t need2 = need + (size_t)384 * 2 * 4160 * 4;
    const int fast  = (ws_size >= need)  ? 1 : 0;
    const int split = (ws_size >= need2) ? 1 : 0;

    if (fast)
        prep_kernel<<<1024, 256, 0, stream>>>(x, Wq, Wk, Wv, Wo, xb, rope);
    qkv_mfma<<<dim3(SEQ / 64, 36), 256, 0, stream>>>(
        x, xb, Wq, Wk, Wv, Wqb, Wkb, Wvb, rope, Qw, Kw, Vw, fast);
    if (split) {
        attn_mfma<<<dim3(96, NH), 256, 0, stream>>>(Qw, Kw, Vw, Ow, part);
        reduce_attn<<<dim3(384), 256, 0, stream>>>(part, Ow);
    } else {
        attn_mfma<<<dim3(64, NH), 256, 0, stream>>>(Qw, Kw, Vw, Ow, part);
    }
    proj_mfma<<<dim3(SEQ / 64, DM / 64), 256, 0, stream>>>(Ow, Wo, Wob, bo, out, fast);
}